// Round 1
// baseline (564.343 us; speedup 1.0000x reference)
//
#include <hip/hip_runtime.h>

// ---------------------------------------------------------------------------
// GCN 2-layer: z' = PReLU(D^-1/2 (A+I) D^-1/2 (z W) + b); outputs (z2, [pool(z1)|pool(z2)])
// Strategy: degree count -> dinv -> CSR-by-dst (counting sort) -> per-layer:
//   f32 GEMM (N x 128 x 128, LDS-tiled) -> gather-aggregate (wave/node) -> pool.
// z1 is stored in d_out's z region (later overwritten by z2), so ws ~30 MB.
// ---------------------------------------------------------------------------

__global__ void deg_kernel(const int* __restrict__ dst, int* __restrict__ degi, int E) {
    int e = blockIdx.x * blockDim.x + threadIdx.x;
    if (e < E) atomicAdd(&degi[dst[e]], 1);
}

__global__ void dinv_kernel(const int* __restrict__ degi, float* __restrict__ dinv, int n) {
    int i = blockIdx.x * blockDim.x + threadIdx.x;
    if (i < n) dinv[i] = rsqrtf((float)(degi[i] + 1));  // +1 = self loop; always > 0
}

// single-block exclusive scan of degi[0..n) -> row_off[0..n], also copies to cursor
__global__ __launch_bounds__(1024) void scan_kernel(const int* __restrict__ degi,
                                                    int* __restrict__ row_off,
                                                    int* __restrict__ cursor, int n) {
    __shared__ int lds[1024];
    __shared__ int carry_s;
    int t = threadIdx.x;
    if (t == 0) carry_s = 0;
    __syncthreads();
    for (int base = 0; base < n; base += 1024) {
        int v = (base + t < n) ? degi[base + t] : 0;
        lds[t] = v;
        __syncthreads();
        for (int off = 1; off < 1024; off <<= 1) {
            int add = (t >= off) ? lds[t - off] : 0;
            __syncthreads();
            lds[t] += add;
            __syncthreads();
        }
        int excl = lds[t] - v;
        if (base + t < n) {
            int ro = carry_s + excl;
            row_off[base + t] = ro;
            cursor[base + t] = ro;
        }
        __syncthreads();
        if (t == 0) carry_s += lds[1023];
        __syncthreads();
    }
    if (t == 0) row_off[n] = carry_s;
}

__global__ void fill_kernel(const int* __restrict__ src, const int* __restrict__ dst,
                            int* __restrict__ cursor, int* __restrict__ col, int E) {
    int e = blockIdx.x * blockDim.x + threadIdx.x;
    if (e < E) {
        int pos = atomicAdd(&cursor[dst[e]], 1);
        col[pos] = src[e];
    }
}

// segment starts for sorted batch: segs[g] = first node index with batch >= g; segs[G] = n
__global__ void seg_kernel(const int* __restrict__ batch, int* __restrict__ segs, int n, int G) {
    int i = blockIdx.x * blockDim.x + threadIdx.x;
    if (i >= n) return;
    int bi = batch[i];
    int bp = (i == 0) ? -1 : batch[i - 1];
    for (int g = bp + 1; g <= bi; ++g) segs[g] = i;
    if (i == n - 1)
        for (int g = bi + 1; g <= G; ++g) segs[g] = n;
}

// Y[nrows,128] = X[nrows,128] @ W[128,128], f32. 64-row tile per block, 256 thr.
// k split in two 64-chunks so LDS stays <= 64 KB (32K W + 17K X).
__global__ __launch_bounds__(256) void gemm128(const float* __restrict__ X,
                                               const float* __restrict__ W,
                                               float* __restrict__ Y, int nrows) {
    __shared__ float Wl[64 * 128];   // W[k0+kk][c]
    __shared__ float Xl[64 * 68];    // X[r][k0+kk], stride 68 (pad, 16B aligned)
    int t = threadIdx.x;
    int tx = t & 15, ty = t >> 4;    // 16 col-groups x 16 row-groups
    int c0 = tx * 8, r0 = ty * 4;
    int row0 = blockIdx.x * 64;
    float acc[4][8] = {};
    for (int k0 = 0; k0 < 128; k0 += 64) {
        // stage W chunk: rows k0..k0+63, all 128 cols (contiguous 32 KB)
        for (int i = t * 4; i < 64 * 128; i += 1024)
            *(float4*)&Wl[i] = *(const float4*)&W[k0 * 128 + i];
        // stage X chunk: 64 rows x 64 cols
        for (int i = t; i < 1024; i += 256) {
            int r = i >> 4, s = i & 15;
            float4 v = {0.f, 0.f, 0.f, 0.f};
            int row = row0 + r;
            if (row < nrows) v = *(const float4*)&X[row * 128 + k0 + s * 4];
            *(float4*)&Xl[r * 68 + s * 4] = v;
        }
        __syncthreads();
        for (int k = 0; k < 64; k += 4) {
            float4 xv[4];
#pragma unroll
            for (int r = 0; r < 4; ++r) xv[r] = *(float4*)&Xl[(r0 + r) * 68 + k];
#pragma unroll
            for (int kk = 0; kk < 4; ++kk) {
                float4 w0 = *(float4*)&Wl[(k + kk) * 128 + c0];
                float4 w1 = *(float4*)&Wl[(k + kk) * 128 + c0 + 4];
                float wv[8] = {w0.x, w0.y, w0.z, w0.w, w1.x, w1.y, w1.z, w1.w};
#pragma unroll
                for (int r = 0; r < 4; ++r) {
                    float xs = ((const float*)&xv[r])[kk];
#pragma unroll
                    for (int j = 0; j < 8; ++j) acc[r][j] += xs * wv[j];
                }
            }
        }
        __syncthreads();
    }
#pragma unroll
    for (int r = 0; r < 4; ++r) {
        int row = row0 + r0 + r;
        if (row < nrows) {
            *(float4*)&Y[row * 128 + c0] =
                make_float4(acc[r][0], acc[r][1], acc[r][2], acc[r][3]);
            *(float4*)&Y[row * 128 + c0 + 4] =
                make_float4(acc[r][4], acc[r][5], acc[r][6], acc[r][7]);
        }
    }
}

// one wave per node: z[i] = PReLU(dinv[i]*(sum_e dinv[s]*zw[s] + dinv[i]*zw[i]) + b)
__global__ __launch_bounds__(256) void agg_kernel(const float* __restrict__ zw,
                                                  const float* __restrict__ dinv,
                                                  const int* __restrict__ row_off,
                                                  const int* __restrict__ col,
                                                  const float* __restrict__ bias,
                                                  const float* __restrict__ alpha,
                                                  float* __restrict__ zout, int n) {
    int wave = blockIdx.x * 4 + (threadIdx.x >> 6);
    int node = __builtin_amdgcn_readfirstlane(wave);
    if (node >= n) return;
    int lane = threadIdx.x & 63;
    int c = lane * 2;
    float di = dinv[node];
    const float2* zwr = (const float2*)zw;
    float2 sv = zwr[node * 64 + lane];
    float ax = di * sv.x, ay = di * sv.y;   // self-loop term (x dinv[i] again at end)
    int e0 = row_off[node], e1 = row_off[node + 1];
    for (int e = e0; e < e1; ++e) {
        int s = col[e];
        float w = dinv[s];
        float2 v = zwr[s * 64 + lane];
        ax += w * v.x;
        ay += w * v.y;
    }
    float zx = di * ax + bias[c];
    float zy = di * ay + bias[c + 1];
    float px = alpha[c], py = alpha[c + 1];
    zx = zx > 0.f ? zx : px * zx;
    zy = zy > 0.f ? zy : py * zy;
    ((float2*)zout)[node * 64 + lane] = make_float2(zx, zy);
}

// one block (128 thr) per graph; batch sorted so rows are contiguous
__global__ __launch_bounds__(128) void pool_kernel(const float* __restrict__ z,
                                                   const int* __restrict__ segs,
                                                   float* __restrict__ gout, int col_off) {
    int g = blockIdx.x, t = threadIdx.x;
    int s0 = segs[g], s1 = segs[g + 1];
    float a = 0.f;
    for (int i = s0; i < s1; ++i) a += z[i * 128 + t];
    gout[g * 256 + col_off + t] = a;
}

extern "C" void kernel_launch(void* const* d_in, const int* in_sizes, int n_in,
                              void* d_out, int out_size, void* d_ws, size_t ws_size,
                              hipStream_t stream) {
    const float* x     = (const float*)d_in[0];
    const int*   eidx  = (const int*)d_in[1];   // [2,E]: src = eidx[0:E), dst = eidx[E:2E)
    const int*   batch = (const int*)d_in[2];
    const float* W1    = (const float*)d_in[3];
    const float* b1    = (const float*)d_in[4];
    const float* W2    = (const float*)d_in[5];
    const float* b2    = (const float*)d_in[6];
    const float* alpha = (const float*)d_in[7];

    const int N = in_sizes[2];
    const int E = in_sizes[1] / 2;
    const int G = (out_size - N * 128) / 256;

    const int* src = eidx;
    const int* dst = eidx + E;

    // workspace layout (256B-aligned offsets)
    char* ws = (char*)d_ws;
    int*   degi    = (int*)(ws + 0);                         // N
    float* dinv    = (float*)(ws + 204800);                  // N
    int*   row_off = (int*)(ws + 409600);                    // N+1
    int*   cursor  = (int*)(ws + 614400);                    // N
    int*   segs    = (int*)(ws + 819200);                    // G+1
    int*   col     = (int*)(ws + 823296);                    // E
    float* zw      = (float*)(ws + 823296 + ((size_t)E * 4 + 255) / 256 * 256); // N*128

    float* z_out = (float*)d_out;            // [N,128]: z1 temporarily, z2 finally
    float* g_out = (float*)d_out + (size_t)N * 128;  // [G,256]

    hipMemsetAsync(degi, 0, (size_t)N * sizeof(int), stream);

    int blkE = (E + 255) / 256;
    int blkN = (N + 255) / 256;
    deg_kernel<<<blkE, 256, 0, stream>>>(dst, degi, E);
    dinv_kernel<<<blkN, 256, 0, stream>>>(degi, dinv, N);
    scan_kernel<<<1, 1024, 0, stream>>>(degi, row_off, cursor, N);
    fill_kernel<<<blkE, 256, 0, stream>>>(src, dst, cursor, col, E);
    seg_kernel<<<blkN, 256, 0, stream>>>(batch, segs, N, G);

    int gemmGrid = (N + 63) / 64;
    int aggGrid  = (N + 3) / 4;

    // layer 1: zw = x@W1 ; z1 = agg(...) -> z_out ; pool1
    gemm128<<<gemmGrid, 256, 0, stream>>>(x, W1, zw, N);
    agg_kernel<<<aggGrid, 256, 0, stream>>>(zw, dinv, row_off, col, b1, alpha, z_out, N);
    pool_kernel<<<G, 128, 0, stream>>>(z_out, segs, g_out, 0);

    // layer 2: zw = z1@W2 ; z2 = agg(...) -> z_out (overwrites z1) ; pool2
    gemm128<<<gemmGrid, 256, 0, stream>>>(z_out, W2, zw, N);
    agg_kernel<<<aggGrid, 256, 0, stream>>>(zw, dinv, row_off, col, b2, alpha, z_out, N);
    pool_kernel<<<G, 128, 0, stream>>>(z_out, segs, g_out, 128);
}

// Round 2
// 378.393 us; speedup vs baseline: 1.4914x; 1.4914x over previous
//
#include <hip/hip_runtime.h>

// ---------------------------------------------------------------------------
// GCN 2-layer: z' = PReLU(D^-1/2 (A+I) D^-1/2 (z W) + b); outputs (z2, [pool(z1)|pool(z2)])
// R1: multi-block scan (was 92.8us single-block = 16% of total);
//     pool split 8-way per graph + atomics; agg edge-loop unroll x2.
// ---------------------------------------------------------------------------

__global__ void deg_kernel(const int* __restrict__ dst, int* __restrict__ degi, int E) {
    int e = blockIdx.x * blockDim.x + threadIdx.x;
    if (e < E) atomicAdd(&degi[dst[e]], 1);
}

__global__ void dinv_kernel(const int* __restrict__ degi, float* __restrict__ dinv, int n) {
    int i = blockIdx.x * blockDim.x + threadIdx.x;
    if (i < n) dinv[i] = rsqrtf((float)(degi[i] + 1));  // +1 = self loop; always > 0
}

// ---- multi-block exclusive scan: A (local scan + block sums), B (scan sums), C (add) ----
__global__ __launch_bounds__(1024) void scanA(const int* __restrict__ degi,
                                              int* __restrict__ row_off,
                                              int* __restrict__ bsum, int n) {
    __shared__ int lds[1024];
    int t = threadIdx.x;
    int base = blockIdx.x * 1024;
    int v = (base + t < n) ? degi[base + t] : 0;
    lds[t] = v;
    __syncthreads();
    for (int off = 1; off < 1024; off <<= 1) {
        int add = (t >= off) ? lds[t - off] : 0;
        __syncthreads();
        lds[t] += add;
        __syncthreads();
    }
    if (base + t < n) row_off[base + t] = lds[t] - v;  // local exclusive
    if (t == 1023) bsum[blockIdx.x] = lds[1023];
}

__global__ __launch_bounds__(64) void scanB(const int* __restrict__ bsum,
                                            int* __restrict__ boff,
                                            int nb, int* __restrict__ row_off, int n) {
    int lane = threadIdx.x;  // one wave
    int v = (lane < nb) ? bsum[lane] : 0;
    int incl = v;
    for (int off = 1; off < 64; off <<= 1) {
        int u = __shfl_up(incl, off, 64);
        if (lane >= off) incl += u;
    }
    if (lane < nb) boff[lane] = incl - v;
    if (lane == 63) row_off[n] = incl;  // grand total
}

__global__ __launch_bounds__(1024) void scanC(int* __restrict__ row_off,
                                              int* __restrict__ cursor,
                                              const int* __restrict__ boff, int n) {
    int i = blockIdx.x * 1024 + threadIdx.x;
    if (i < n) {
        int ro = row_off[i] + boff[blockIdx.x];
        row_off[i] = ro;
        cursor[i] = ro;
    }
}

__global__ void fill_kernel(const int* __restrict__ src, const int* __restrict__ dst,
                            int* __restrict__ cursor, int* __restrict__ col, int E) {
    int e = blockIdx.x * blockDim.x + threadIdx.x;
    if (e < E) {
        int pos = atomicAdd(&cursor[dst[e]], 1);
        col[pos] = src[e];
    }
}

// segment starts for sorted batch: segs[g] = first node index with batch >= g; segs[G] = n
__global__ void seg_kernel(const int* __restrict__ batch, int* __restrict__ segs, int n, int G) {
    int i = blockIdx.x * blockDim.x + threadIdx.x;
    if (i >= n) return;
    int bi = batch[i];
    int bp = (i == 0) ? -1 : batch[i - 1];
    for (int g = bp + 1; g <= bi; ++g) segs[g] = i;
    if (i == n - 1)
        for (int g = bi + 1; g <= G; ++g) segs[g] = n;
}

// Y[nrows,128] = X[nrows,128] @ W[128,128], f32. 64-row tile per block, 256 thr.
__global__ __launch_bounds__(256) void gemm128(const float* __restrict__ X,
                                               const float* __restrict__ W,
                                               float* __restrict__ Y, int nrows) {
    __shared__ float Wl[64 * 128];   // W[k0+kk][c]
    __shared__ float Xl[64 * 68];    // X[r][k0+kk], stride 68 (pad, 16B aligned)
    int t = threadIdx.x;
    int tx = t & 15, ty = t >> 4;    // 16 col-groups x 16 row-groups
    int c0 = tx * 8, r0 = ty * 4;
    int row0 = blockIdx.x * 64;
    float acc[4][8] = {};
    for (int k0 = 0; k0 < 128; k0 += 64) {
        for (int i = t * 4; i < 64 * 128; i += 1024)
            *(float4*)&Wl[i] = *(const float4*)&W[k0 * 128 + i];
        for (int i = t; i < 1024; i += 256) {
            int r = i >> 4, s = i & 15;
            float4 v = {0.f, 0.f, 0.f, 0.f};
            int row = row0 + r;
            if (row < nrows) v = *(const float4*)&X[row * 128 + k0 + s * 4];
            *(float4*)&Xl[r * 68 + s * 4] = v;
        }
        __syncthreads();
        for (int k = 0; k < 64; k += 4) {
            float4 xv[4];
#pragma unroll
            for (int r = 0; r < 4; ++r) xv[r] = *(float4*)&Xl[(r0 + r) * 68 + k];
#pragma unroll
            for (int kk = 0; kk < 4; ++kk) {
                float4 w0 = *(float4*)&Wl[(k + kk) * 128 + c0];
                float4 w1 = *(float4*)&Wl[(k + kk) * 128 + c0 + 4];
                float wv[8] = {w0.x, w0.y, w0.z, w0.w, w1.x, w1.y, w1.z, w1.w};
#pragma unroll
                for (int r = 0; r < 4; ++r) {
                    float xs = ((const float*)&xv[r])[kk];
#pragma unroll
                    for (int j = 0; j < 8; ++j) acc[r][j] += xs * wv[j];
                }
            }
        }
        __syncthreads();
    }
#pragma unroll
    for (int r = 0; r < 4; ++r) {
        int row = row0 + r0 + r;
        if (row < nrows) {
            *(float4*)&Y[row * 128 + c0] =
                make_float4(acc[r][0], acc[r][1], acc[r][2], acc[r][3]);
            *(float4*)&Y[row * 128 + c0 + 4] =
                make_float4(acc[r][4], acc[r][5], acc[r][6], acc[r][7]);
        }
    }
}

// one wave per node: z[i] = PReLU(dinv[i]*(sum_e dinv[s]*zw[s] + dinv[i]*zw[i]) + b)
__global__ __launch_bounds__(256) void agg_kernel(const float* __restrict__ zw,
                                                  const float* __restrict__ dinv,
                                                  const int* __restrict__ row_off,
                                                  const int* __restrict__ col,
                                                  const float* __restrict__ bias,
                                                  const float* __restrict__ alpha,
                                                  float* __restrict__ zout, int n) {
    int wave = blockIdx.x * 4 + (threadIdx.x >> 6);
    int node = __builtin_amdgcn_readfirstlane(wave);
    if (node >= n) return;
    int lane = threadIdx.x & 63;
    int c = lane * 2;
    float di = dinv[node];
    const float2* zwr = (const float2*)zw;
    float2 sv = zwr[node * 64 + lane];
    float ax = di * sv.x, ay = di * sv.y;   // self-loop term (x dinv[i] again at end)
    float bx = 0.f, by = 0.f;
    int e0 = row_off[node], e1 = row_off[node + 1];
    int e = e0;
    for (; e + 1 < e1; e += 2) {
        int s0 = col[e], s1 = col[e + 1];
        float w0 = dinv[s0], w1 = dinv[s1];
        float2 v0 = zwr[s0 * 64 + lane];
        float2 v1 = zwr[s1 * 64 + lane];
        ax += w0 * v0.x; ay += w0 * v0.y;
        bx += w1 * v1.x; by += w1 * v1.y;
    }
    if (e < e1) {
        int s = col[e];
        float w = dinv[s];
        float2 v = zwr[s * 64 + lane];
        ax += w * v.x; ay += w * v.y;
    }
    ax += bx; ay += by;
    float zx = di * ax + bias[c];
    float zy = di * ay + bias[c + 1];
    float px = alpha[c], py = alpha[c + 1];
    zx = zx > 0.f ? zx : px * zx;
    zy = zy > 0.f ? zy : py * zy;
    ((float2*)zout)[node * 64 + lane] = make_float2(zx, zy);
}

// 8 blocks per graph, 128 thr each; partial sums atomicAdd'ed into zeroed g_out
#define PSPLIT 8
__global__ __launch_bounds__(128) void pool_kernel(const float* __restrict__ z,
                                                   const int* __restrict__ segs,
                                                   float* __restrict__ gout, int col_off) {
    int g = blockIdx.x / PSPLIT, q = blockIdx.x % PSPLIT;
    int t = threadIdx.x;
    int s0 = segs[g], s1 = segs[g + 1];
    int len = s1 - s0;
    int c0 = s0 + (int)(((long long)len * q) / PSPLIT);
    int c1 = s0 + (int)(((long long)len * (q + 1)) / PSPLIT);
    float a = 0.f;
    for (int i = c0; i < c1; ++i) a += z[i * 128 + t];
    if (c1 > c0) atomicAdd(&gout[g * 256 + col_off + t], a);
}

extern "C" void kernel_launch(void* const* d_in, const int* in_sizes, int n_in,
                              void* d_out, int out_size, void* d_ws, size_t ws_size,
                              hipStream_t stream) {
    const float* x     = (const float*)d_in[0];
    const int*   eidx  = (const int*)d_in[1];   // [2,E]: src = eidx[0:E), dst = eidx[E:2E)
    const int*   batch = (const int*)d_in[2];
    const float* W1    = (const float*)d_in[3];
    const float* b1    = (const float*)d_in[4];
    const float* W2    = (const float*)d_in[5];
    const float* b2    = (const float*)d_in[6];
    const float* alpha = (const float*)d_in[7];

    const int N = in_sizes[2];
    const int E = in_sizes[1] / 2;
    const int G = (out_size - N * 128) / 256;

    const int* src = eidx;
    const int* dst = eidx + E;

    // workspace layout (aligned offsets)
    char* ws = (char*)d_ws;
    int*   degi    = (int*)(ws + 0);          // N
    float* dinv    = (float*)(ws + 204800);   // N
    int*   row_off = (int*)(ws + 409600);     // N+1
    int*   cursor  = (int*)(ws + 614400);     // N
    int*   segs    = (int*)(ws + 819200);     // G+1
    int*   bsum    = (int*)(ws + 820480);     // 64
    int*   boff    = (int*)(ws + 820736);     // 64
    int*   col     = (int*)(ws + 820992);     // E
    float* zw      = (float*)(ws + 820992 + (size_t)E * 4);  // N*128 (offset stays 256-aligned for E%64==0)

    float* z_out = (float*)d_out;                     // [N,128]: z1 temporarily, z2 finally
    float* g_out = (float*)d_out + (size_t)N * 128;   // [G,256]

    hipMemsetAsync(degi, 0, (size_t)N * sizeof(int), stream);
    hipMemsetAsync(g_out, 0, (size_t)G * 256 * sizeof(float), stream);

    int blkE = (E + 255) / 256;
    int blkN = (N + 255) / 256;
    int nb   = (N + 1023) / 1024;

    deg_kernel<<<blkE, 256, 0, stream>>>(dst, degi, E);
    dinv_kernel<<<blkN, 256, 0, stream>>>(degi, dinv, N);
    scanA<<<nb, 1024, 0, stream>>>(degi, row_off, bsum, N);
    scanB<<<1, 64, 0, stream>>>(bsum, boff, nb, row_off, N);
    scanC<<<nb, 1024, 0, stream>>>(row_off, cursor, boff, N);
    fill_kernel<<<blkE, 256, 0, stream>>>(src, dst, cursor, col, E);
    seg_kernel<<<blkN, 256, 0, stream>>>(batch, segs, N, G);

    int gemmGrid = (N + 63) / 64;
    int aggGrid  = (N + 3) / 4;

    // layer 1: zw = x@W1 ; z1 = agg(...) -> z_out ; pool1
    gemm128<<<gemmGrid, 256, 0, stream>>>(x, W1, zw, N);
    agg_kernel<<<aggGrid, 256, 0, stream>>>(zw, dinv, row_off, col, b1, alpha, z_out, N);
    pool_kernel<<<G * PSPLIT, 128, 0, stream>>>(z_out, segs, g_out, 0);

    // layer 2: zw = z1@W2 ; z2 = agg(...) -> z_out (overwrites z1) ; pool2
    gemm128<<<gemmGrid, 256, 0, stream>>>(z_out, W2, zw, N);
    agg_kernel<<<aggGrid, 256, 0, stream>>>(zw, dinv, row_off, col, b2, alpha, z_out, N);
    pool_kernel<<<G * PSPLIT, 128, 0, stream>>>(z_out, segs, g_out, 128);
}

// Round 3
// 304.083 us; speedup vs baseline: 1.8559x; 1.2444x over previous
//
#include <hip/hip_runtime.h>
#include <stdint.h>

// ---------------------------------------------------------------------------
// GCN 2-layer: z' = PReLU(D^-1/2 (A+I) D^-1/2 (z W) + b); outputs (z2, [pool(z1)|pool(z2)])
// R2: zw stored bf16 (halves gather traffic: 256B/row); GEMM -> MFMA bf16
//     (16x16x32) with pre-transposed bf16 W; agg gather unroll x4.
// ---------------------------------------------------------------------------

typedef __attribute__((ext_vector_type(8))) short short8;
typedef __attribute__((ext_vector_type(4))) float f32x4;

__device__ __forceinline__ uint16_t bf16rne(float f) {
    uint32_t u = __float_as_uint(f);
    uint32_t r = (u + 0x7fffu + ((u >> 16) & 1u)) >> 16;
    return (uint16_t)r;
}

__global__ void deg_kernel(const int* __restrict__ dst, int* __restrict__ degi, int E) {
    int e = blockIdx.x * blockDim.x + threadIdx.x;
    if (e < E) atomicAdd(&degi[dst[e]], 1);
}

__global__ void dinv_kernel(const int* __restrict__ degi, float* __restrict__ dinv, int n) {
    int i = blockIdx.x * blockDim.x + threadIdx.x;
    if (i < n) dinv[i] = rsqrtf((float)(degi[i] + 1));  // +1 = self loop; always > 0
}

// ---- multi-block exclusive scan ----
__global__ __launch_bounds__(1024) void scanA(const int* __restrict__ degi,
                                              int* __restrict__ row_off,
                                              int* __restrict__ bsum, int n) {
    __shared__ int lds[1024];
    int t = threadIdx.x;
    int base = blockIdx.x * 1024;
    int v = (base + t < n) ? degi[base + t] : 0;
    lds[t] = v;
    __syncthreads();
    for (int off = 1; off < 1024; off <<= 1) {
        int add = (t >= off) ? lds[t - off] : 0;
        __syncthreads();
        lds[t] += add;
        __syncthreads();
    }
    if (base + t < n) row_off[base + t] = lds[t] - v;  // local exclusive
    if (t == 1023) bsum[blockIdx.x] = lds[1023];
}

__global__ __launch_bounds__(64) void scanB(const int* __restrict__ bsum,
                                            int* __restrict__ boff,
                                            int nb, int* __restrict__ row_off, int n) {
    int lane = threadIdx.x;  // one wave
    int v = (lane < nb) ? bsum[lane] : 0;
    int incl = v;
    for (int off = 1; off < 64; off <<= 1) {
        int u = __shfl_up(incl, off, 64);
        if (lane >= off) incl += u;
    }
    if (lane < nb) boff[lane] = incl - v;
    if (lane == 63) row_off[n] = incl;  // grand total
}

__global__ __launch_bounds__(1024) void scanC(int* __restrict__ row_off,
                                              int* __restrict__ cursor,
                                              const int* __restrict__ boff, int n) {
    int i = blockIdx.x * 1024 + threadIdx.x;
    if (i < n) {
        int ro = row_off[i] + boff[blockIdx.x];
        row_off[i] = ro;
        cursor[i] = ro;
    }
}

__global__ void fill_kernel(const int* __restrict__ src, const int* __restrict__ dst,
                            int* __restrict__ cursor, int* __restrict__ col, int E) {
    int e = blockIdx.x * blockDim.x + threadIdx.x;
    if (e < E) {
        int pos = atomicAdd(&cursor[dst[e]], 1);
        col[pos] = src[e];
    }
}

__global__ void seg_kernel(const int* __restrict__ batch, int* __restrict__ segs, int n, int G) {
    int i = blockIdx.x * blockDim.x + threadIdx.x;
    if (i >= n) return;
    int bi = batch[i];
    int bp = (i == 0) ? -1 : batch[i - 1];
    for (int g = bp + 1; g <= bi; ++g) segs[g] = i;
    if (i == n - 1)
        for (int g = bi + 1; g <= G; ++g) segs[g] = n;
}

// W [128][128] f32 row-major -> Wt [n][k] bf16 (transposed), for both layers
__global__ void prep_w(const float* __restrict__ W1, const float* __restrict__ W2,
                       uint16_t* __restrict__ Wt1, uint16_t* __restrict__ Wt2) {
    int tid = blockIdx.x * 256 + threadIdx.x;  // 0..32767
    const float* W = (tid & 16384) ? W2 : W1;
    uint16_t* O = (tid & 16384) ? Wt2 : Wt1;
    int rem = tid & 16383;
    int k = rem >> 7, n = rem & 127;
    O[n * 128 + k] = bf16rne(W[rem]);
}

// Y[nrows][128] (bf16) = bf16(X[nrows][128] f32) @ W ; Wt is bf16 [n][k].
// 64 rows/block, 4 waves: wave w owns rows w*16..w*16+15, all 128 cols.
#define LDW 136  // LDS row pitch in elements (272B: 16B-aligned, dword-stride 68 -> <=2-way on frag reads)
__global__ __launch_bounds__(256) void gemm_mfma(const float* __restrict__ X,
                                                 const uint16_t* __restrict__ Wt,
                                                 uint16_t* __restrict__ Y, int nrows) {
    __shared__ uint16_t Wl[128 * LDW];
    __shared__ uint16_t Xl[64 * LDW];
    int t = threadIdx.x;
    int lane = t & 63, w = t >> 6;
    int row0 = blockIdx.x * 64;

    // stage Wt (bf16, contiguous 16B chunks)
    for (int c = t; c < 2048; c += 256) {
        int r = c >> 4, co = (c & 15) * 8;
        *(short8*)&Wl[r * LDW + co] = *(const short8*)&Wt[r * 128 + co];
    }
    // stage X (f32 -> bf16)
    for (int c = t; c < 2048; c += 256) {
        int r = c >> 5, co = (c & 31) * 4;
        float4 v = make_float4(0.f, 0.f, 0.f, 0.f);
        if (row0 + r < nrows) v = *(const float4*)&X[(size_t)(row0 + r) * 128 + co];
        uint32_t lo = (uint32_t)bf16rne(v.x) | ((uint32_t)bf16rne(v.y) << 16);
        uint32_t hi = (uint32_t)bf16rne(v.z) | ((uint32_t)bf16rne(v.w) << 16);
        uint2 p = make_uint2(lo, hi);
        *(uint2*)&Xl[r * LDW + co] = p;
    }
    __syncthreads();

    int m = lane & 15, quad = lane >> 4;
    f32x4 acc[8];
#pragma unroll
    for (int i = 0; i < 8; ++i) acc[i] = (f32x4){0.f, 0.f, 0.f, 0.f};

#pragma unroll
    for (int ks = 0; ks < 4; ++ks) {
        short8 a = *(short8*)&Xl[(w * 16 + m) * LDW + ks * 32 + quad * 8];
#pragma unroll
        for (int n0 = 0; n0 < 8; ++n0) {
            short8 b = *(short8*)&Wl[(n0 * 16 + m) * LDW + ks * 32 + quad * 8];
            acc[n0] = __builtin_amdgcn_mfma_f32_16x16x32_bf16(a, b, acc[n0], 0, 0, 0);
        }
    }

    // epilogue: stash C tiles (bf16) into this wave's own Xl rows, then coalesced store.
    // C/D layout: col = lane&15, row = (lane>>4)*4 + reg.
#pragma unroll
    for (int n0 = 0; n0 < 8; ++n0)
#pragma unroll
        for (int r = 0; r < 4; ++r) {
            int row = quad * 4 + r;
            Xl[(w * 16 + row) * LDW + n0 * 16 + m] = bf16rne(acc[n0][r]);
        }
    for (int r16 = 0; r16 < 16; ++r16) {
        int row = row0 + w * 16 + r16;
        if (row < nrows) {
            uint32_t v = *(uint32_t*)&Xl[(w * 16 + r16) * LDW + lane * 2];
            ((uint32_t*)Y)[(size_t)row * 64 + lane] = v;
        }
    }
}

// one wave per node: z[i] = PReLU(dinv[i]*(sum_e dinv[s]*zw[s] + dinv[i]*zw[i]) + b)
// zw rows are bf16 (packed pairs): lane reads one dword = channels {2*lane, 2*lane+1}.
__device__ __forceinline__ float bf_lo(uint32_t v) { return __uint_as_float(v << 16); }
__device__ __forceinline__ float bf_hi(uint32_t v) { return __uint_as_float(v & 0xffff0000u); }

__global__ __launch_bounds__(256) void agg_kernel(const uint32_t* __restrict__ zw,
                                                  const float* __restrict__ dinv,
                                                  const int* __restrict__ row_off,
                                                  const int* __restrict__ col,
                                                  const float* __restrict__ bias,
                                                  const float* __restrict__ alpha,
                                                  float* __restrict__ zout, int n) {
    int wave = blockIdx.x * 4 + (threadIdx.x >> 6);
    int node = __builtin_amdgcn_readfirstlane(wave);
    if (node >= n) return;
    int lane = threadIdx.x & 63;
    int c = lane * 2;
    float di = dinv[node];
    uint32_t sv = zw[node * 64 + lane];
    float ax = di * bf_lo(sv), ay = di * bf_hi(sv);  // self-loop (x dinv[i] again at end)
    float bx = 0.f, by = 0.f;
    int e0 = row_off[node], e1 = row_off[node + 1];
    int e = e0;
    for (; e + 3 < e1; e += 4) {
        int s0 = col[e], s1 = col[e + 1], s2 = col[e + 2], s3 = col[e + 3];
        float w0 = dinv[s0], w1 = dinv[s1], w2 = dinv[s2], w3 = dinv[s3];
        uint32_t v0 = zw[s0 * 64 + lane];
        uint32_t v1 = zw[s1 * 64 + lane];
        uint32_t v2 = zw[s2 * 64 + lane];
        uint32_t v3 = zw[s3 * 64 + lane];
        ax += w0 * bf_lo(v0); ay += w0 * bf_hi(v0);
        bx += w1 * bf_lo(v1); by += w1 * bf_hi(v1);
        ax += w2 * bf_lo(v2); ay += w2 * bf_hi(v2);
        bx += w3 * bf_lo(v3); by += w3 * bf_hi(v3);
    }
    for (; e < e1; ++e) {
        int s = col[e];
        float w = dinv[s];
        uint32_t v = zw[s * 64 + lane];
        ax += w * bf_lo(v); ay += w * bf_hi(v);
    }
    ax += bx; ay += by;
    float zx = di * ax + bias[c];
    float zy = di * ay + bias[c + 1];
    float px = alpha[c], py = alpha[c + 1];
    zx = zx > 0.f ? zx : px * zx;
    zy = zy > 0.f ? zy : py * zy;
    ((float2*)zout)[node * 64 + lane] = make_float2(zx, zy);
}

// 8 blocks per graph, 128 thr each; partials atomicAdd'ed into zeroed g_out
#define PSPLIT 8
__global__ __launch_bounds__(128) void pool_kernel(const float* __restrict__ z,
                                                   const int* __restrict__ segs,
                                                   float* __restrict__ gout, int col_off) {
    int g = blockIdx.x / PSPLIT, q = blockIdx.x % PSPLIT;
    int t = threadIdx.x;
    int s0 = segs[g], s1 = segs[g + 1];
    int len = s1 - s0;
    int c0 = s0 + (int)(((long long)len * q) / PSPLIT);
    int c1 = s0 + (int)(((long long)len * (q + 1)) / PSPLIT);
    float a = 0.f;
    for (int i = c0; i < c1; ++i) a += z[i * 128 + t];
    if (c1 > c0) atomicAdd(&gout[g * 256 + col_off + t], a);
}

extern "C" void kernel_launch(void* const* d_in, const int* in_sizes, int n_in,
                              void* d_out, int out_size, void* d_ws, size_t ws_size,
                              hipStream_t stream) {
    const float* x     = (const float*)d_in[0];
    const int*   eidx  = (const int*)d_in[1];   // [2,E]
    const int*   batch = (const int*)d_in[2];
    const float* W1    = (const float*)d_in[3];
    const float* b1    = (const float*)d_in[4];
    const float* W2    = (const float*)d_in[5];
    const float* b2    = (const float*)d_in[6];
    const float* alpha = (const float*)d_in[7];

    const int N = in_sizes[2];
    const int E = in_sizes[1] / 2;
    const int G = (out_size - N * 128) / 256;

    const int* src = eidx;
    const int* dst = eidx + E;

    // workspace layout (all offsets 256B-aligned)
    char* ws = (char*)d_ws;
    size_t off = 0;
    auto alloc = [&](size_t bytes) { void* p = ws + off; off = (off + bytes + 255) & ~(size_t)255; return p; };
    int*      degi    = (int*)alloc((size_t)N * 4);
    float*    dinv    = (float*)alloc((size_t)N * 4);
    int*      row_off = (int*)alloc((size_t)(N + 1) * 4);
    int*      cursor  = (int*)alloc((size_t)N * 4);
    int*      segs    = (int*)alloc((size_t)(G + 1) * 4);
    int*      bsum    = (int*)alloc(64 * 4);
    int*      boff    = (int*)alloc(64 * 4);
    int*      col     = (int*)alloc((size_t)E * 4);
    uint32_t* zw      = (uint32_t*)alloc((size_t)N * 128 * 2);  // bf16 [N][128]
    uint16_t* Wt1     = (uint16_t*)alloc(128 * 128 * 2);
    uint16_t* Wt2     = (uint16_t*)alloc(128 * 128 * 2);

    float* z_out = (float*)d_out;                     // [N,128]
    float* g_out = (float*)d_out + (size_t)N * 128;   // [G,256]

    hipMemsetAsync(degi, 0, (size_t)N * sizeof(int), stream);
    hipMemsetAsync(g_out, 0, (size_t)G * 256 * sizeof(float), stream);

    int blkE = (E + 255) / 256;
    int blkN = (N + 255) / 256;
    int nb   = (N + 1023) / 1024;

    prep_w<<<128, 256, 0, stream>>>(W1, W2, Wt1, Wt2);
    deg_kernel<<<blkE, 256, 0, stream>>>(dst, degi, E);
    dinv_kernel<<<blkN, 256, 0, stream>>>(degi, dinv, N);
    scanA<<<nb, 1024, 0, stream>>>(degi, row_off, bsum, N);
    scanB<<<1, 64, 0, stream>>>(bsum, boff, nb, row_off, N);
    scanC<<<nb, 1024, 0, stream>>>(row_off, cursor, boff, N);
    fill_kernel<<<blkE, 256, 0, stream>>>(src, dst, cursor, col, E);
    seg_kernel<<<blkN, 256, 0, stream>>>(batch, segs, N, G);

    int gemmGrid = (N + 63) / 64;
    int aggGrid  = (N + 3) / 4;

    gemm_mfma<<<gemmGrid, 256, 0, stream>>>(x, Wt1, (uint16_t*)zw, N);
    agg_kernel<<<aggGrid, 256, 0, stream>>>(zw, dinv, row_off, col, b1, alpha, z_out, N);
    pool_kernel<<<G * PSPLIT, 128, 0, stream>>>(z_out, segs, g_out, 0);

    gemm_mfma<<<gemmGrid, 256, 0, stream>>>(z_out, Wt2, (uint16_t*)zw, N);
    agg_kernel<<<aggGrid, 256, 0, stream>>>(zw, dinv, row_off, col, b2, alpha, z_out, N);
    pool_kernel<<<G * PSPLIT, 128, 0, stream>>>(z_out, segs, g_out, 128);
}

// Round 4
// 277.697 us; speedup vs baseline: 2.0322x; 1.0950x over previous
//
#include <hip/hip_runtime.h>
#include <stdint.h>

// ---------------------------------------------------------------------------
// GCN 2-layer. R3: MLP x4 in deg/fill scatter phases; heterogeneous-fused
// launches: K1=deg+prep_w+seg, K5=gemm1(+)fill interleaved, K7=gemm2(+)pool1.
// dinv folded into scanA. 11 launches total.
// ---------------------------------------------------------------------------

typedef __attribute__((ext_vector_type(8))) short short8;
typedef __attribute__((ext_vector_type(4))) float f32x4;

__device__ __forceinline__ uint16_t bf16rne(float f) {
    uint32_t u = __float_as_uint(f);
    uint32_t r = (u + 0x7fffu + ((u >> 16) & 1u)) >> 16;
    return (uint16_t)r;
}
__device__ __forceinline__ float bf_lo(uint32_t v) { return __uint_as_float(v << 16); }
__device__ __forceinline__ float bf_hi(uint32_t v) { return __uint_as_float(v & 0xffff0000u); }

// ---- K1: deg (4 edges/thread) + prep_w + seg ----
__global__ __launch_bounds__(256) void k1(const int* __restrict__ dst, int* __restrict__ degi,
                                          int E, int nbE,
                                          const float* __restrict__ W1, const float* __restrict__ W2,
                                          uint16_t* __restrict__ Wt1, uint16_t* __restrict__ Wt2,
                                          const int* __restrict__ batch, int* __restrict__ segs,
                                          int N, int G) {
    int bid = blockIdx.x, t = threadIdx.x;
    if (bid < nbE) {
        int base = bid * 1024 + t;
        int d[4];
#pragma unroll
        for (int k = 0; k < 4; ++k) { int e = base + k * 256; d[k] = (e < E) ? dst[e] : -1; }
#pragma unroll
        for (int k = 0; k < 4; ++k) if (d[k] >= 0) atomicAdd(&degi[d[k]], 1);
    } else if (bid < nbE + 128) {
        int p = (bid - nbE) * 256 + t;   // 0..32767
        const float* W = (p & 16384) ? W2 : W1;
        uint16_t* O = (p & 16384) ? Wt2 : Wt1;
        int rem = p & 16383;
        int kk = rem >> 7, nn = rem & 127;
        O[nn * 128 + kk] = bf16rne(W[rem]);
    } else {
        int i = (bid - nbE - 128) * 256 + t;
        if (i >= N) return;
        int bi = batch[i];
        int bp = (i == 0) ? -1 : batch[i - 1];
        for (int g = bp + 1; g <= bi; ++g) segs[g] = i;
        if (i == N - 1)
            for (int g = bi + 1; g <= G; ++g) segs[g] = N;
    }
}

// ---- scan (A: local scan + dinv; B: block sums; C: add offsets) ----
__global__ __launch_bounds__(1024) void scanA(const int* __restrict__ degi,
                                              float* __restrict__ dinv,
                                              int* __restrict__ row_off,
                                              int* __restrict__ bsum, int n) {
    __shared__ int lds[1024];
    int t = threadIdx.x;
    int base = blockIdx.x * 1024;
    int v = (base + t < n) ? degi[base + t] : 0;
    if (base + t < n) dinv[base + t] = rsqrtf((float)(v + 1));
    lds[t] = v;
    __syncthreads();
    for (int off = 1; off < 1024; off <<= 1) {
        int add = (t >= off) ? lds[t - off] : 0;
        __syncthreads();
        lds[t] += add;
        __syncthreads();
    }
    if (base + t < n) row_off[base + t] = lds[t] - v;
    if (t == 1023) bsum[blockIdx.x] = lds[1023];
}

__global__ __launch_bounds__(64) void scanB(const int* __restrict__ bsum,
                                            int* __restrict__ boff,
                                            int nb, int* __restrict__ row_off, int n) {
    int lane = threadIdx.x;
    int v = (lane < nb) ? bsum[lane] : 0;
    int incl = v;
    for (int off = 1; off < 64; off <<= 1) {
        int u = __shfl_up(incl, off, 64);
        if (lane >= off) incl += u;
    }
    if (lane < nb) boff[lane] = incl - v;
    if (lane == 63) row_off[n] = incl;
}

__global__ __launch_bounds__(1024) void scanC(int* __restrict__ row_off,
                                              int* __restrict__ cursor,
                                              const int* __restrict__ boff, int n) {
    int i = blockIdx.x * 1024 + threadIdx.x;
    if (i < n) {
        int ro = row_off[i] + boff[blockIdx.x];
        row_off[i] = ro;
        cursor[i] = ro;
    }
}

// ---- gemm body: Y[nrows][128] bf16 = bf16(X) @ W, Wt bf16 [n][k] ----
#define LDW 136
__device__ __forceinline__ void gemm_body(const float* __restrict__ X,
                                          const uint16_t* __restrict__ Wt,
                                          uint16_t* __restrict__ Y, int nrows,
                                          int bid, int t) {
    __shared__ uint16_t Wl[128 * LDW];
    __shared__ uint16_t Xl[64 * LDW];
    int lane = t & 63, w = t >> 6;
    int row0 = bid * 64;

    for (int c = t; c < 2048; c += 256) {
        int r = c >> 4, co = (c & 15) * 8;
        *(short8*)&Wl[r * LDW + co] = *(const short8*)&Wt[r * 128 + co];
    }
    for (int c = t; c < 2048; c += 256) {
        int r = c >> 5, co = (c & 31) * 4;
        float4 v = make_float4(0.f, 0.f, 0.f, 0.f);
        if (row0 + r < nrows) v = *(const float4*)&X[(size_t)(row0 + r) * 128 + co];
        uint32_t lo = (uint32_t)bf16rne(v.x) | ((uint32_t)bf16rne(v.y) << 16);
        uint32_t hi = (uint32_t)bf16rne(v.z) | ((uint32_t)bf16rne(v.w) << 16);
        *(uint2*)&Xl[r * LDW + co] = make_uint2(lo, hi);
    }
    __syncthreads();

    int m = lane & 15, quad = lane >> 4;
    f32x4 acc[8];
#pragma unroll
    for (int i = 0; i < 8; ++i) acc[i] = (f32x4){0.f, 0.f, 0.f, 0.f};

#pragma unroll
    for (int ks = 0; ks < 4; ++ks) {
        short8 a = *(short8*)&Xl[(w * 16 + m) * LDW + ks * 32 + quad * 8];
#pragma unroll
        for (int n0 = 0; n0 < 8; ++n0) {
            short8 b = *(short8*)&Wl[(n0 * 16 + m) * LDW + ks * 32 + quad * 8];
            acc[n0] = __builtin_amdgcn_mfma_f32_16x16x32_bf16(a, b, acc[n0], 0, 0, 0);
        }
    }
    __syncthreads();
#pragma unroll
    for (int n0 = 0; n0 < 8; ++n0)
#pragma unroll
        for (int r = 0; r < 4; ++r)
            Xl[(w * 16 + quad * 4 + r) * LDW + n0 * 16 + m] = bf16rne(acc[n0][r]);
    for (int r16 = 0; r16 < 16; ++r16) {
        int row = row0 + w * 16 + r16;
        if (row < nrows) {
            uint32_t v = *(uint32_t*)&Xl[(w * 16 + r16) * LDW + lane * 2];
            ((uint32_t*)Y)[(size_t)row * 64 + lane] = v;
        }
    }
}

// ---- fill body: 4 edges/thread, batched phases for MLP ----
__device__ __forceinline__ void fill_body(const int* __restrict__ src, const int* __restrict__ dst,
                                          int* __restrict__ cursor, int* __restrict__ col,
                                          int E, int fb, int t) {
    int base = fb * 1024 + t;
    int d[4], s[4], p[4];
#pragma unroll
    for (int k = 0; k < 4; ++k) {
        int e = base + k * 256;
        d[k] = (e < E) ? dst[e] : -1;
        s[k] = (e < E) ? src[e] : 0;
    }
#pragma unroll
    for (int k = 0; k < 4; ++k) if (d[k] >= 0) p[k] = atomicAdd(&cursor[d[k]], 1);
#pragma unroll
    for (int k = 0; k < 4; ++k) if (d[k] >= 0) col[p[k]] = s[k];
}

// ---- pool body: 256 thr, 8 chunks/graph across 4 blocks ----
__device__ __forceinline__ void pool_body(const float* __restrict__ z, const int* __restrict__ segs,
                                          float* __restrict__ gout, int col_off, int pb, int t) {
    int g = pb >> 2;
    int q = ((pb & 3) << 1) | (t >> 7);
    int c = t & 127;
    int s0 = segs[g], s1 = segs[g + 1], len = s1 - s0;
    int c0 = s0 + (int)(((long long)len * q) >> 3);
    int c1 = s0 + (int)(((long long)len * (q + 1)) >> 3);
    float a = 0.f;
    for (int i = c0; i < c1; ++i) a += z[(size_t)i * 128 + c];
    if (c1 > c0) atomicAdd(&gout[g * 256 + col_off + c], a);
}

// ---- K5: gemm1 (+) fill, interleaved ----
__global__ __launch_bounds__(256) void k5(const float* __restrict__ X, const uint16_t* __restrict__ Wt,
                                          uint16_t* __restrict__ Y, int nrows, int gemmGrid,
                                          const int* __restrict__ src, const int* __restrict__ dst,
                                          int* __restrict__ cursor, int* __restrict__ col,
                                          int E, int fillGrid) {
    int bid = blockIdx.x, t = threadIdx.x;
    int mn = min(gemmGrid, fillGrid);
    int role, idx;
    if (bid < 2 * mn) { role = bid & 1; idx = bid >> 1; }
    else { role = (gemmGrid > fillGrid) ? 0 : 1; idx = bid - 2 * mn + mn; }
    if (role == 0) gemm_body(X, Wt, Y, nrows, idx, t);
    else fill_body(src, dst, cursor, col, E, idx, t);
}

// ---- K7: gemm2 (+) pool1, interleaved ----
__global__ __launch_bounds__(256) void k7(const float* __restrict__ X, const uint16_t* __restrict__ Wt,
                                          uint16_t* __restrict__ Y, int nrows, int gemmGrid,
                                          const float* __restrict__ z, const int* __restrict__ segs,
                                          float* __restrict__ gout, int col_off, int poolGrid) {
    int bid = blockIdx.x, t = threadIdx.x;
    int mn = min(gemmGrid, poolGrid);
    int role, idx;
    if (bid < 2 * mn) { role = bid & 1; idx = bid >> 1; }
    else { role = (gemmGrid > poolGrid) ? 0 : 1; idx = bid - 2 * mn + mn; }
    if (role == 0) gemm_body(X, Wt, Y, nrows, idx, t);
    else pool_body(z, segs, gout, col_off, idx, t);
}

// ---- standalone pool (K9) ----
__global__ __launch_bounds__(256) void poolk(const float* __restrict__ z, const int* __restrict__ segs,
                                             float* __restrict__ gout, int col_off) {
    pool_body(z, segs, gout, col_off, blockIdx.x, threadIdx.x);
}

// ---- agg: one wave per node, bf16 gather ----
__global__ __launch_bounds__(256) void agg_kernel(const uint32_t* __restrict__ zw,
                                                  const float* __restrict__ dinv,
                                                  const int* __restrict__ row_off,
                                                  const int* __restrict__ col,
                                                  const float* __restrict__ bias,
                                                  const float* __restrict__ alpha,
                                                  float* __restrict__ zout, int n) {
    int wave = blockIdx.x * 4 + (threadIdx.x >> 6);
    int node = __builtin_amdgcn_readfirstlane(wave);
    if (node >= n) return;
    int lane = threadIdx.x & 63;
    int c = lane * 2;
    float di = dinv[node];
    uint32_t sv = zw[node * 64 + lane];
    float ax = di * bf_lo(sv), ay = di * bf_hi(sv);
    float bx = 0.f, by = 0.f;
    int e0 = row_off[node], e1 = row_off[node + 1];
    int e = e0;
    for (; e + 3 < e1; e += 4) {
        int s0 = col[e], s1 = col[e + 1], s2 = col[e + 2], s3 = col[e + 3];
        float w0 = dinv[s0], w1 = dinv[s1], w2 = dinv[s2], w3 = dinv[s3];
        uint32_t v0 = zw[s0 * 64 + lane];
        uint32_t v1 = zw[s1 * 64 + lane];
        uint32_t v2 = zw[s2 * 64 + lane];
        uint32_t v3 = zw[s3 * 64 + lane];
        ax += w0 * bf_lo(v0); ay += w0 * bf_hi(v0);
        bx += w1 * bf_lo(v1); by += w1 * bf_hi(v1);
        ax += w2 * bf_lo(v2); ay += w2 * bf_hi(v2);
        bx += w3 * bf_lo(v3); by += w3 * bf_hi(v3);
    }
    for (; e < e1; ++e) {
        int s = col[e];
        float w = dinv[s];
        uint32_t v = zw[s * 64 + lane];
        ax += w * bf_lo(v); ay += w * bf_hi(v);
    }
    ax += bx; ay += by;
    float zx = di * ax + bias[c];
    float zy = di * ay + bias[c + 1];
    float px = alpha[c], py = alpha[c + 1];
    zx = zx > 0.f ? zx : px * zx;
    zy = zy > 0.f ? zy : py * zy;
    ((float2*)zout)[node * 64 + lane] = make_float2(zx, zy);
}

extern "C" void kernel_launch(void* const* d_in, const int* in_sizes, int n_in,
                              void* d_out, int out_size, void* d_ws, size_t ws_size,
                              hipStream_t stream) {
    const float* x     = (const float*)d_in[0];
    const int*   eidx  = (const int*)d_in[1];
    const int*   batch = (const int*)d_in[2];
    const float* W1    = (const float*)d_in[3];
    const float* b1    = (const float*)d_in[4];
    const float* W2    = (const float*)d_in[5];
    const float* b2    = (const float*)d_in[6];
    const float* alpha = (const float*)d_in[7];

    const int N = in_sizes[2];
    const int E = in_sizes[1] / 2;
    const int G = (out_size - N * 128) / 256;

    const int* src = eidx;
    const int* dst = eidx + E;

    char* ws = (char*)d_ws;
    size_t off = 0;
    auto alloc = [&](size_t bytes) { void* p = ws + off; off = (off + bytes + 255) & ~(size_t)255; return p; };
    int*      degi    = (int*)alloc((size_t)N * 4);
    float*    dinv    = (float*)alloc((size_t)N * 4);
    int*      row_off = (int*)alloc((size_t)(N + 1) * 4);
    int*      cursor  = (int*)alloc((size_t)N * 4);
    int*      segs    = (int*)alloc((size_t)(G + 1) * 4);
    int*      bsum    = (int*)alloc(64 * 4);
    int*      boff    = (int*)alloc(64 * 4);
    int*      col     = (int*)alloc((size_t)E * 4);
    uint32_t* zw      = (uint32_t*)alloc((size_t)N * 128 * 2);
    uint16_t* Wt1     = (uint16_t*)alloc(128 * 128 * 2);
    uint16_t* Wt2     = (uint16_t*)alloc(128 * 128 * 2);

    float* z_out = (float*)d_out;
    float* g_out = (float*)d_out + (size_t)N * 128;

    hipMemsetAsync(degi, 0, (size_t)N * sizeof(int), stream);
    hipMemsetAsync(g_out, 0, (size_t)G * 256 * sizeof(float), stream);

    int nbE = (E + 1023) / 1024;           // deg/fill blocks (4 edges/thread)
    int nbS = (N + 255) / 256;             // seg blocks
    int nb  = (N + 1023) / 1024;           // scan blocks
    int gemmGrid = (N + 63) / 64;
    int aggGrid  = (N + 3) / 4;
    int poolGrid = G * 4;

    k1<<<nbE + 128 + nbS, 256, 0, stream>>>(dst, degi, E, nbE, W1, W2, Wt1, Wt2, batch, segs, N, G);
    scanA<<<nb, 1024, 0, stream>>>(degi, dinv, row_off, bsum, N);
    scanB<<<1, 64, 0, stream>>>(bsum, boff, nb, row_off, N);
    scanC<<<nb, 1024, 0, stream>>>(row_off, cursor, boff, N);

    k5<<<gemmGrid + nbE, 256, 0, stream>>>(x, Wt1, (uint16_t*)zw, N, gemmGrid,
                                           src, dst, cursor, col, E, nbE);
    agg_kernel<<<aggGrid, 256, 0, stream>>>(zw, dinv, row_off, col, b1, alpha, z_out, N);

    k7<<<gemmGrid + poolGrid, 256, 0, stream>>>(z_out, Wt2, (uint16_t*)zw, N, gemmGrid,
                                                z_out, segs, g_out, 0, poolGrid);
    agg_kernel<<<aggGrid, 256, 0, stream>>>(zw, dinv, row_off, col, b2, alpha, z_out, N);
    poolk<<<poolGrid, 256, 0, stream>>>(z_out, segs, g_out, 128);
}

// Round 5
// 271.241 us; speedup vs baseline: 2.0806x; 1.0238x over previous
//
#include <hip/hip_runtime.h>
#include <stdint.h>

// ---------------------------------------------------------------------------
// GCN 2-layer. R4: pool fused into agg (4-node LDS reduce + block atomics);
// z1 kept bf16 in ws (gemm2 reads bf16, no cvt); scanB folded into scanC;
// gemm core barrier removed (LDS traffic is wave-private). 9 launches.
// ---------------------------------------------------------------------------

typedef __attribute__((ext_vector_type(8))) short short8;
typedef __attribute__((ext_vector_type(4))) float f32x4;

__device__ __forceinline__ uint16_t bf16rne(float f) {
    uint32_t u = __float_as_uint(f);
    uint32_t r = (u + 0x7fffu + ((u >> 16) & 1u)) >> 16;
    return (uint16_t)r;
}
__device__ __forceinline__ float bf_lo(uint32_t v) { return __uint_as_float(v << 16); }
__device__ __forceinline__ float bf_hi(uint32_t v) { return __uint_as_float(v & 0xffff0000u); }

// ---- K1: deg (4 edges/thread) + prep_w + seg-free (segs unused now) ----
__global__ __launch_bounds__(256) void k1(const int* __restrict__ dst, int* __restrict__ degi,
                                          int E, int nbE,
                                          const float* __restrict__ W1, const float* __restrict__ W2,
                                          uint16_t* __restrict__ Wt1, uint16_t* __restrict__ Wt2) {
    int bid = blockIdx.x, t = threadIdx.x;
    if (bid < nbE) {
        int base = bid * 1024 + t;
        int d[4];
#pragma unroll
        for (int k = 0; k < 4; ++k) { int e = base + k * 256; d[k] = (e < E) ? dst[e] : -1; }
#pragma unroll
        for (int k = 0; k < 4; ++k) if (d[k] >= 0) atomicAdd(&degi[d[k]], 1);
    } else {
        int p = (bid - nbE) * 256 + t;   // 0..32767
        const float* W = (p & 16384) ? W2 : W1;
        uint16_t* O = (p & 16384) ? Wt2 : Wt1;
        int rem = p & 16383;
        int kk = rem >> 7, nn = rem & 127;
        O[nn * 128 + kk] = bf16rne(W[rem]);
    }
}

// ---- scanA: local scan + dinv + block sums ----
__global__ __launch_bounds__(1024) void scanA(const int* __restrict__ degi,
                                              float* __restrict__ dinv,
                                              int* __restrict__ row_off,
                                              int* __restrict__ bsum, int n) {
    __shared__ int lds[1024];
    int t = threadIdx.x;
    int base = blockIdx.x * 1024;
    int v = (base + t < n) ? degi[base + t] : 0;
    if (base + t < n) dinv[base + t] = rsqrtf((float)(v + 1));
    lds[t] = v;
    __syncthreads();
    for (int off = 1; off < 1024; off <<= 1) {
        int add = (t >= off) ? lds[t - off] : 0;
        __syncthreads();
        lds[t] += add;
        __syncthreads();
    }
    if (base + t < n) row_off[base + t] = lds[t] - v;
    if (t == 1023) bsum[blockIdx.x] = lds[1023];
}

// ---- scanC: each block wave-scans bsum itself, adds offset (nb <= 64) ----
__global__ __launch_bounds__(1024) void scanC(int* __restrict__ row_off,
                                              int* __restrict__ cursor,
                                              const int* __restrict__ bsum,
                                              int nb, int n) {
    __shared__ int boff_s;
    int t = threadIdx.x;
    if (t < 64) {
        int v = (t < nb) ? bsum[t] : 0;
        int incl = v;
        for (int off = 1; off < 64; off <<= 1) {
            int u = __shfl_up(incl, off, 64);
            if (t >= off) incl += u;
        }
        if (t == (int)blockIdx.x) boff_s = incl - v;
        if (blockIdx.x == 0 && t == nb - 1) row_off[n] = incl;
    }
    __syncthreads();
    int i = blockIdx.x * 1024 + t;
    if (i < n) {
        int ro = row_off[i] + boff_s;
        row_off[i] = ro;
        cursor[i] = ro;
    }
}

// ---- gemm core (after staging): wave-private LDS rows, no barrier needed ----
#define LDW 136
__device__ __forceinline__ void gemm_core(const uint16_t* Wl, uint16_t* Xl,
                                          uint16_t* __restrict__ Y, int nrows,
                                          int row0, int lane, int w) {
    int m = lane & 15, quad = lane >> 4;
    f32x4 acc[8];
#pragma unroll
    for (int i = 0; i < 8; ++i) acc[i] = (f32x4){0.f, 0.f, 0.f, 0.f};
#pragma unroll
    for (int ks = 0; ks < 4; ++ks) {
        short8 a = *(short8*)&Xl[(w * 16 + m) * LDW + ks * 32 + quad * 8];
#pragma unroll
        for (int n0 = 0; n0 < 8; ++n0) {
            short8 b = *(const short8*)&Wl[(n0 * 16 + m) * LDW + ks * 32 + quad * 8];
            acc[n0] = __builtin_amdgcn_mfma_f32_16x16x32_bf16(a, b, acc[n0], 0, 0, 0);
        }
    }
    // epilogue: C/D layout col=lane&15, row=(lane>>4)*4+reg; stash bf16 in own rows
#pragma unroll
    for (int n0 = 0; n0 < 8; ++n0)
#pragma unroll
        for (int r = 0; r < 4; ++r)
            Xl[(w * 16 + quad * 4 + r) * LDW + n0 * 16 + m] = bf16rne(acc[n0][r]);
    for (int r16 = 0; r16 < 16; ++r16) {
        int row = row0 + w * 16 + r16;
        if (row < nrows) {
            uint32_t v = *(uint32_t*)&Xl[(w * 16 + r16) * LDW + lane * 2];
            ((uint32_t*)Y)[(size_t)row * 64 + lane] = v;
        }
    }
}

// ---- gemm body, f32 input (layer 1) ----
__device__ __forceinline__ void gemm_body_f32(const float* __restrict__ X,
                                              const uint16_t* __restrict__ Wt,
                                              uint16_t* __restrict__ Y, int nrows,
                                              int bid, int t) {
    __shared__ uint16_t Wl[128 * LDW];
    __shared__ uint16_t Xl[64 * LDW];
    int lane = t & 63, w = t >> 6;
    int row0 = bid * 64;
    for (int c = t; c < 2048; c += 256) {
        int r = c >> 4, co = (c & 15) * 8;
        *(short8*)&Wl[r * LDW + co] = *(const short8*)&Wt[r * 128 + co];
    }
    for (int c = t; c < 2048; c += 256) {
        int r = c >> 5, co = (c & 31) * 4;
        float4 v = make_float4(0.f, 0.f, 0.f, 0.f);
        if (row0 + r < nrows) v = *(const float4*)&X[(size_t)(row0 + r) * 128 + co];
        uint32_t lo = (uint32_t)bf16rne(v.x) | ((uint32_t)bf16rne(v.y) << 16);
        uint32_t hi = (uint32_t)bf16rne(v.z) | ((uint32_t)bf16rne(v.w) << 16);
        *(uint2*)&Xl[r * LDW + co] = make_uint2(lo, hi);
    }
    __syncthreads();
    gemm_core(Wl, Xl, Y, nrows, row0, lane, w);
}

// ---- gemm kernel, bf16 input (layer 2) ----
__global__ __launch_bounds__(256) void gemm_bf(const uint16_t* __restrict__ Xb,
                                               const uint16_t* __restrict__ Wt,
                                               uint16_t* __restrict__ Y, int nrows) {
    __shared__ uint16_t Wl[128 * LDW];
    __shared__ uint16_t Xl[64 * LDW];
    int t = threadIdx.x;
    int lane = t & 63, w = t >> 6;
    int row0 = blockIdx.x * 64;
    for (int c = t; c < 2048; c += 256) {
        int r = c >> 4, co = (c & 15) * 8;
        *(short8*)&Wl[r * LDW + co] = *(const short8*)&Wt[r * 128 + co];
    }
    for (int c = t; c < 1024; c += 256) {
        int r = c >> 4, co = (c & 15) * 8;
        short8 v = {0, 0, 0, 0, 0, 0, 0, 0};
        if (row0 + r < nrows) v = *(const short8*)&Xb[(size_t)(row0 + r) * 128 + co];
        *(short8*)&Xl[r * LDW + co] = v;
    }
    __syncthreads();
    gemm_core(Wl, Xl, Y, nrows, row0, lane, w);
}

// ---- fill body: 4 edges/thread, batched phases ----
__device__ __forceinline__ void fill_body(const int* __restrict__ src, const int* __restrict__ dst,
                                          int* __restrict__ cursor, int* __restrict__ col,
                                          int E, int fb, int t) {
    int base = fb * 1024 + t;
    int d[4], s[4], p[4];
#pragma unroll
    for (int k = 0; k < 4; ++k) {
        int e = base + k * 256;
        d[k] = (e < E) ? dst[e] : -1;
        s[k] = (e < E) ? src[e] : 0;
    }
#pragma unroll
    for (int k = 0; k < 4; ++k) if (d[k] >= 0) p[k] = atomicAdd(&cursor[d[k]], 1);
#pragma unroll
    for (int k = 0; k < 4; ++k) if (d[k] >= 0) col[p[k]] = s[k];
}

// ---- K5: gemm1 (+) fill, interleaved ----
__global__ __launch_bounds__(256) void k5(const float* __restrict__ X, const uint16_t* __restrict__ Wt,
                                          uint16_t* __restrict__ Y, int nrows, int gemmGrid,
                                          const int* __restrict__ src, const int* __restrict__ dst,
                                          int* __restrict__ cursor, int* __restrict__ col,
                                          int E, int fillGrid) {
    int bid = blockIdx.x, t = threadIdx.x;
    int mn = min(gemmGrid, fillGrid);
    int role, idx;
    if (bid < 2 * mn) { role = bid & 1; idx = bid >> 1; }
    else { role = (gemmGrid > fillGrid) ? 0 : 1; idx = bid - 2 * mn + mn; }
    if (role == 0) gemm_body_f32(X, Wt, Y, nrows, idx, t);
    else fill_body(src, dst, cursor, col, E, idx, t);
}

// ---- agg + fused pool: 4 waves = 4 nodes per block ----
// mode 0: z -> z1b (bf16 packed); mode 1: z -> zoutf (f32, final output)
__global__ __launch_bounds__(256) void aggp(const uint32_t* __restrict__ zw,
                                            const float* __restrict__ dinv,
                                            const int* __restrict__ row_off,
                                            const int* __restrict__ col,
                                            const float* __restrict__ bias,
                                            const float* __restrict__ alpha,
                                            const int* __restrict__ batch,
                                            float* __restrict__ gout, int col_off,
                                            uint32_t* __restrict__ z1b,
                                            float* __restrict__ zoutf,
                                            int mode, int n) {
    __shared__ int gsh[4];
    __shared__ float red[4][128];
    int wv = threadIdx.x >> 6;
    int lane = threadIdx.x & 63;
    int node = blockIdx.x * 4 + wv;
    bool valid = node < n;
    int nc = __builtin_amdgcn_readfirstlane(valid ? node : (n - 1));
    int c = lane * 2;
    float di = dinv[nc];
    uint32_t sv = zw[(size_t)nc * 64 + lane];
    float ax = di * bf_lo(sv), ay = di * bf_hi(sv);  // self-loop (x di again below)
    float bx = 0.f, by = 0.f;
    int e0 = row_off[nc], e1 = row_off[nc + 1];
    int e = e0;
    for (; e + 3 < e1; e += 4) {
        int s0 = col[e], s1 = col[e + 1], s2 = col[e + 2], s3 = col[e + 3];
        float w0 = dinv[s0], w1 = dinv[s1], w2 = dinv[s2], w3 = dinv[s3];
        uint32_t v0 = zw[(size_t)s0 * 64 + lane];
        uint32_t v1 = zw[(size_t)s1 * 64 + lane];
        uint32_t v2 = zw[(size_t)s2 * 64 + lane];
        uint32_t v3 = zw[(size_t)s3 * 64 + lane];
        ax += w0 * bf_lo(v0); ay += w0 * bf_hi(v0);
        bx += w1 * bf_lo(v1); by += w1 * bf_hi(v1);
        ax += w2 * bf_lo(v2); ay += w2 * bf_hi(v2);
        bx += w3 * bf_lo(v3); by += w3 * bf_hi(v3);
    }
    for (; e < e1; ++e) {
        int s = col[e];
        float w = dinv[s];
        uint32_t v = zw[(size_t)s * 64 + lane];
        ax += w * bf_lo(v); ay += w * bf_hi(v);
    }
    ax += bx; ay += by;
    float zx = di * ax + bias[c];
    float zy = di * ay + bias[c + 1];
    float px = alpha[c], py = alpha[c + 1];
    zx = zx > 0.f ? zx : px * zx;
    zy = zy > 0.f ? zy : py * zy;

    if (valid) {
        if (mode == 0) {
            uint32_t pk = (uint32_t)bf16rne(zx) | ((uint32_t)bf16rne(zy) << 16);
            z1b[(size_t)nc * 64 + lane] = pk;
        } else {
            ((float2*)zoutf)[(size_t)nc * 64 + lane] = make_float2(zx, zy);
        }
    }

    // fused global_add_pool
    int g = batch[nc];
    float cx = valid ? zx : 0.f, cy = valid ? zy : 0.f;
    if (lane == 0) gsh[wv] = valid ? g : -1 - wv;
    __syncthreads();
    bool uni = (gsh[0] == gsh[1]) && (gsh[1] == gsh[2]) && (gsh[2] == gsh[3]);
    if (uni) {  // common case: all 4 nodes in same graph (batch sorted)
        red[wv][c] = cx; red[wv][c + 1] = cy;
        __syncthreads();
        if (wv == 0) {
            float sx = red[0][c] + red[1][c] + red[2][c] + red[3][c];
            float sy = red[0][c + 1] + red[1][c + 1] + red[2][c + 1] + red[3][c + 1];
            float* base = &gout[(size_t)g * 256 + col_off];
            atomicAdd(&base[c], sx);
            atomicAdd(&base[c + 1], sy);
        }
    } else if (valid) {
        float* base = &gout[(size_t)g * 256 + col_off];
        atomicAdd(&base[c], cx);
        atomicAdd(&base[c + 1], cy);
    }
}

extern "C" void kernel_launch(void* const* d_in, const int* in_sizes, int n_in,
                              void* d_out, int out_size, void* d_ws, size_t ws_size,
                              hipStream_t stream) {
    const float* x     = (const float*)d_in[0];
    const int*   eidx  = (const int*)d_in[1];
    const int*   batch = (const int*)d_in[2];
    const float* W1    = (const float*)d_in[3];
    const float* b1    = (const float*)d_in[4];
    const float* W2    = (const float*)d_in[5];
    const float* b2    = (const float*)d_in[6];
    const float* alpha = (const float*)d_in[7];

    const int N = in_sizes[2];
    const int E = in_sizes[1] / 2;
    const int G = (out_size - N * 128) / 256;

    const int* src = eidx;
    const int* dst = eidx + E;

    char* ws = (char*)d_ws;
    size_t off = 0;
    auto alloc = [&](size_t bytes) { void* p = ws + off; off = (off + bytes + 255) & ~(size_t)255; return p; };
    int*      degi    = (int*)alloc((size_t)N * 4);
    float*    dinv    = (float*)alloc((size_t)N * 4);
    int*      row_off = (int*)alloc((size_t)(N + 1) * 4);
    int*      cursor  = (int*)alloc((size_t)N * 4);
    int*      bsum    = (int*)alloc(64 * 4);
    int*      col     = (int*)alloc((size_t)E * 4);
    uint32_t* zw      = (uint32_t*)alloc((size_t)N * 128 * 2);
    uint32_t* z1b     = (uint32_t*)alloc((size_t)N * 128 * 2);
    uint16_t* Wt1     = (uint16_t*)alloc(128 * 128 * 2);
    uint16_t* Wt2     = (uint16_t*)alloc(128 * 128 * 2);

    float* z_out = (float*)d_out;
    float* g_out = (float*)d_out + (size_t)N * 128;

    hipMemsetAsync(degi, 0, (size_t)N * sizeof(int), stream);
    hipMemsetAsync(g_out, 0, (size_t)G * 256 * sizeof(float), stream);

    int nbE = (E + 1023) / 1024;
    int nb  = (N + 1023) / 1024;
    int gemmGrid = (N + 63) / 64;
    int aggGrid  = (N + 3) / 4;

    k1<<<nbE + 128, 256, 0, stream>>>(dst, degi, E, nbE, W1, W2, Wt1, Wt2);
    scanA<<<nb, 1024, 0, stream>>>(degi, dinv, row_off, bsum, N);
    scanC<<<nb, 1024, 0, stream>>>(row_off, cursor, bsum, nb, N);

    k5<<<gemmGrid + nbE, 256, 0, stream>>>(x, Wt1, (uint16_t*)zw, N, gemmGrid,
                                           src, dst, cursor, col, E, nbE);
    aggp<<<aggGrid, 256, 0, stream>>>(zw, dinv, row_off, col, b1, alpha, batch,
                                      g_out, 0, z1b, nullptr, 0, N);
    gemm_bf<<<gemmGrid, 256, 0, stream>>>((const uint16_t*)z1b, Wt2, (uint16_t*)zw, N);
    aggp<<<aggGrid, 256, 0, stream>>>(zw, dinv, row_off, col, b2, alpha, batch,
                                      g_out, 128, nullptr, z_out, 1, N);
}